// Round 5
// baseline (930.297 us; speedup 1.0000x reference)
//
#include <hip/hip_runtime.h>
#include <hip/hip_bf16.h>
#include <math.h>

#define NRES 768
#define CS   384
#define CZ   128
#define CH   16
#define NH   12
#define PQK  4
#define PV   8
#define QCOLS   (NH*CH)        // 192
#define KVCOLS  (2*NH*CH)      // 384
#define QPCOLS  (NH*PQK*3)     // 144
#define KVPCOLS (NH*(PQK+PV)*3)// 432
#define CATC    (NH*(CZ+CH+PV*4)) // 2112
#define NN      (NRES*NRES)    // 589824

static __device__ __forceinline__ unsigned pack_bf16(float a, float b) {
    unsigned ua = __float_as_uint(a);
    unsigned ub = __float_as_uint(b);
    ua = (ua + 0x7fffu + ((ua >> 16) & 1u)) >> 16;
    ub = (ub + 0x7fffu + ((ub >> 16) & 1u)) & 0xffff0000u;
    return ua | ub;
}
#define BFLO(u) __uint_as_float((u) << 16)
#define BFHI(u) __uint_as_float((u) & 0xffff0000u)

// ---------------- proj: tiled GEMM s(768x384) @ {Wq|Wkv|Wqp|Wkvp}; 32x48 tiles ----------------
__global__ __launch_bounds__(256) void proj_kernel(
    const float* __restrict__ s,
    const float* __restrict__ Wq,  const float* __restrict__ bq,
    const float* __restrict__ Wkv, const float* __restrict__ bkv,
    const float* __restrict__ Wqp, const float* __restrict__ bqp,
    const float* __restrict__ Wkvp,const float* __restrict__ bkvp,
    float* __restrict__ proj_q, float* __restrict__ proj_kv,
    float* __restrict__ proj_qp, float* __restrict__ proj_kvp)
{
    __shared__ float Al[32][36];   // [k][m], 32 rows
    __shared__ float Bl[32][52];   // [k][n], 48 cols
    const int mt = blockIdx.x;     // 0..23 (32 rows each)
    const int gc0 = blockIdx.y * 48;
    const float* W; const float* bb; int ncol; float* dst; int c0;
    if (gc0 < 192)      { W=Wq;   bb=bq;   ncol=QCOLS;   dst=proj_q;   c0=gc0; }
    else if (gc0 < 576) { W=Wkv;  bb=bkv;  ncol=KVCOLS;  dst=proj_kv;  c0=gc0-192; }
    else if (gc0 < 720) { W=Wqp;  bb=bqp;  ncol=QPCOLS;  dst=proj_qp;  c0=gc0-576; }
    else                { W=Wkvp; bb=bkvp; ncol=KVPCOLS; dst=proj_kvp; c0=gc0-720; }
    const int tid = threadIdx.x;
    const int m0 = (tid & 15)*2;
    const int n0 = (tid >> 4)*3;
    float acc[2][3] = {};
    for (int kc = 0; kc < CS; kc += 32) {
        {
            int r = tid >> 3, c4 = (tid & 7)*4;
            float4 v = *(const float4*)(s + (size_t)(mt*32+r)*CS + kc + c4);
            Al[c4][r]=v.x; Al[c4+1][r]=v.y; Al[c4+2][r]=v.z; Al[c4+3][r]=v.w;
        }
        for (int f = tid; f < 384; f += 256) {
            int r = f / 12, c4 = (f % 12)*4;
            *(float4*)&Bl[r][c4] = *(const float4*)(W + (size_t)(kc+r)*ncol + c0 + c4);
        }
        __syncthreads();
        #pragma unroll
        for (int kk = 0; kk < 32; ++kk) {
            float2 a = *(const float2*)&Al[kk][m0];
            float b0 = Bl[kk][n0], b1 = Bl[kk][n0+1], b2 = Bl[kk][n0+2];
            acc[0][0]+=a.x*b0; acc[0][1]+=a.x*b1; acc[0][2]+=a.x*b2;
            acc[1][0]+=a.y*b0; acc[1][1]+=a.y*b1; acc[1][2]+=a.y*b2;
        }
        __syncthreads();
    }
    #pragma unroll
    for (int r = 0; r < 2; ++r)
        #pragma unroll
        for (int c = 0; c < 3; ++c)
            dst[(size_t)(mt*32+m0+r)*ncol + c0+n0+c] = acc[r][c] + bb[c0+n0+c];
}

// ---------------- rotpts: points + packed layouts + out bias-init + cat opair zero ----------------
__global__ __launch_bounds__(256) void rotpts_kernel(
    const float* __restrict__ rot, const float* __restrict__ trans,
    const float* __restrict__ proj_q, const float* __restrict__ proj_kv,
    const float* __restrict__ proj_qp, const float* __restrict__ proj_kvp,
    const float* __restrict__ b_out,
    float* __restrict__ qfrag, float* __restrict__ kcat, float* __restrict__ vcatT,
    float* __restrict__ out, float* __restrict__ cat)
{
    int g = blockIdx.x*256 + threadIdx.x;
    const int S0 = NRES*48;            // q points
    const int S1 = S0 + NRES*432;      // kv point comps
    const int S2 = S1 + NRES*192;      // proj_q -> qfrag
    const int S3 = S2 + NRES*384;      // proj_kv -> kcat/vcatT
    const int S4 = S3 + NRES*CS;       // out bias init
    const int S5 = S4 + NRES*1536;     // cat o_pair zero
    if (g < S0) {
        int n = g/48, rem = g%48;
        int h = rem>>2, p = rem&3;
        float p0 = proj_qp[(size_t)n*QPCOLS + rem];
        float p1 = proj_qp[(size_t)n*QPCOLS + 48 + rem];
        float p2 = proj_qp[(size_t)n*QPCOLS + 96 + rem];
        const float* Rm = rot + (size_t)n*9; const float* t = trans + (size_t)n*3;
        float* dq = qfrag + ((size_t)n*12 + h)*28 + 16 + p*3;
        #pragma unroll
        for (int i = 0; i < 3; ++i)
            dq[i] = Rm[i*3]*p0 + Rm[i*3+1]*p1 + Rm[i*3+2]*p2 + t[i];
    } else if (g < S1) {
        int g2 = g - S0;
        int n = g2 % 768, t = g2 / 768;   // t in [0,432)
        int h = t/36, u = t%36, p = u/3, i = u%3;
        int col = h*12 + p;
        float p0 = proj_kvp[(size_t)n*KVPCOLS + col];
        float p1 = proj_kvp[(size_t)n*KVPCOLS + 144 + col];
        float p2 = proj_kvp[(size_t)n*KVPCOLS + 288 + col];
        float val = rot[(size_t)n*9 + i*3]*p0 + rot[(size_t)n*9 + i*3+1]*p1
                  + rot[(size_t)n*9 + i*3+2]*p2 + trans[(size_t)n*3 + i];
        if (p < PQK) kcat[(size_t)(h*28 + 16 + p*3 + i)*NRES + n] = val;
        else         vcatT[(size_t)(h*40 + 16 + (p-4)*3 + i)*NRES + n] = val;
    } else if (g < S2) {
        int g3 = g - S1;
        int n = g3 / 192, c = g3 % 192;
        int h = c >> 4, cc = c & 15;
        qfrag[((size_t)n*12 + h)*28 + cc] = proj_q[(size_t)n*QCOLS + c];
    } else if (g < S3) {
        int g4 = g - S2;
        int n = g4 % 768, col = g4 / 768;   // col in [0,384)
        int h = col >> 5, cc = col & 31;
        float val = proj_kv[(size_t)n*KVCOLS + col];
        if (cc < 16) kcat[(size_t)(h*28 + cc)*NRES + n] = val;
        else         vcatT[(size_t)(h*40 + (cc-16))*NRES + n] = val;
    } else if (g < S4) {
        int g5 = g - S3;
        out[g5] = b_out[g5 % CS];
    } else if (g < S5) {
        int g6 = g - S4;
        int q = g6 / 1536, c = g6 % 1536;
        cat[(size_t)q*CATC + 576 + c] = 0.f;
    }
}

// ---------------- bias: lg = scale_b*(z@W_b + b_b) + mask  AND  zh = bf16(z) ----------------
__global__ __launch_bounds__(256) void bias_kernel(
    const float* __restrict__ z, const float* __restrict__ mask,
    const float* __restrict__ W_b, const float* __restrict__ b_b,
    float* __restrict__ lg, unsigned short* __restrict__ zh)
{
    int r = blockIdx.x*256 + threadIdx.x;     // 0..589823 = q*768+k
    int q = r / 768, k = r - q*768;
    const float4* zr = (const float4*)(z + (size_t)r*CZ);
    unsigned* zhr = (unsigned*)(zh + (size_t)r*CZ);
    float acc[12] = {};
    #pragma unroll
    for (int c4 = 0; c4 < 32; ++c4) {
        float4 v = zr[c4];
        const float* w0 = W_b + c4*48;        // wave-uniform -> scalar loads
        #pragma unroll
        for (int h = 0; h < 12; ++h)
            acc[h] += v.x*w0[h] + v.y*w0[12+h] + v.z*w0[24+h] + v.w*w0[36+h];
        uint2 u; u.x = pack_bf16(v.x, v.y); u.y = pack_bf16(v.z, v.w);
        *(uint2*)(zhr + c4*2) = u;
    }
    float mterm = 100000.0f*(mask[q]*mask[k] - 1.0f);
    const float scale_b = 0.5773502691896258f;   // sqrt(1/3)
    #pragma unroll
    for (int h = 0; h < 12; ++h)
        lg[(size_t)h*NN + r] = scale_b*(acc[h] + b_b[h]) + mterm;
}

// ---------------- softmax_fused: qk+pt logits + softmax + o + o_pt ----------------
// block = (h, 8 consecutive q), wave per q.
__global__ __launch_bounds__(512) void softmax_fused_kernel(
    float* __restrict__ lg, const float* __restrict__ qfrag, const float* __restrict__ kcat,
    const float* __restrict__ head_w, const float* __restrict__ vcatT,
    float* __restrict__ cat, float* __restrict__ optt)
{
    const int h = blockIdx.x % 12;
    const int q = (blockIdx.x / 12)*8 + (threadIdx.x >> 6);
    const int ln = threadIdx.x & 63;
    const float scale_qk = 0.14433756729740643f;  // sqrt(1/48)
    float x = head_w[h];
    float sp = (x > 20.f) ? x : log1pf(__expf(x));
    float coef = -0.5f * sp * 0.13608276348795434f;   // sqrt(1/54)

    float qf[28];
    const float* qp = qfrag + ((size_t)q*12 + h)*28;
    #pragma unroll
    for (int c = 0; c < 28; ++c) qf[c] = qp[c];

    float* arow = lg + (size_t)h*NN + (size_t)q*NRES;
    const float* kb = kcat + (size_t)h*28*NRES;
    float4 a[3];
    #pragma unroll
    for (int i = 0; i < 3; ++i) {
        a[i] = *(const float4*)(arow + ln*4 + i*256);
        float4 d = {0.f,0.f,0.f,0.f}, p2 = {0.f,0.f,0.f,0.f};
        #pragma unroll
        for (int c = 0; c < 16; ++c) {
            float4 kv = *(const float4*)(kb + (size_t)c*NRES + ln*4 + i*256);
            d.x += qf[c]*kv.x; d.y += qf[c]*kv.y; d.z += qf[c]*kv.z; d.w += qf[c]*kv.w;
        }
        #pragma unroll
        for (int c = 16; c < 28; ++c) {
            float4 kv = *(const float4*)(kb + (size_t)c*NRES + ln*4 + i*256);
            float t0 = qf[c]-kv.x, t1 = qf[c]-kv.y, t2 = qf[c]-kv.z, t3 = qf[c]-kv.w;
            p2.x += t0*t0; p2.y += t1*t1; p2.z += t2*t2; p2.w += t3*t3;
        }
        a[i].x += scale_qk*d.x + coef*p2.x;
        a[i].y += scale_qk*d.y + coef*p2.y;
        a[i].z += scale_qk*d.z + coef*p2.z;
        a[i].w += scale_qk*d.w + coef*p2.w;
    }
    float m = -1e30f;
    #pragma unroll
    for (int i=0;i<3;++i) m = fmaxf(m, fmaxf(fmaxf(a[i].x,a[i].y),fmaxf(a[i].z,a[i].w)));
    #pragma unroll
    for (int o=32;o>0;o>>=1) m = fmaxf(m, __shfl_xor(m,o,64));
    float ssum = 0.f;
    #pragma unroll
    for (int i=0;i<3;++i) {
        a[i].x = __expf(a[i].x-m); a[i].y = __expf(a[i].y-m);
        a[i].z = __expf(a[i].z-m); a[i].w = __expf(a[i].w-m);
        ssum += a[i].x + a[i].y + a[i].z + a[i].w;
    }
    #pragma unroll
    for (int o=32;o>0;o>>=1) ssum += __shfl_xor(ssum,o,64);
    float inv = 1.f/ssum;
    #pragma unroll
    for (int i=0;i<3;++i) {
        a[i].x*=inv; a[i].y*=inv; a[i].z*=inv; a[i].w*=inv;
        *(float4*)(arow + ln*4 + i*256) = a[i];
    }
    for (int col = 0; col < 40; ++col) {
        const float* vrow = vcatT + (size_t)(h*40+col)*NRES;
        float p = 0.f;
        #pragma unroll
        for (int i=0;i<3;++i) {
            float4 v = *(const float4*)(vrow + ln*4 + i*256);
            p += a[i].x*v.x + a[i].y*v.y + a[i].z*v.z + a[i].w*v.w;
        }
        #pragma unroll
        for (int o=32;o>0;o>>=1) p += __shfl_xor(p,o,64);
        if (ln == 0) {
            if (col < 16) cat[(size_t)q*CATC + h*16 + col] = p;
            else          optt[(size_t)q*288 + h*24 + (col-16)] = p;
        }
    }
}

// ---------------- o_pair: block=(q, khalf); bf16 z stream; atomicAdd into cat ----------------
__global__ __launch_bounds__(192) void opair_kernel(
    const unsigned short* __restrict__ zh, const float* __restrict__ lg,
    const float* __restrict__ rot, const float* __restrict__ trans,
    const float* __restrict__ optt, float* __restrict__ cat)
{
    __shared__ float abuf[12*385];
    const int q = blockIdx.x >> 1, half = blockIdx.x & 1;
    const int tid = threadIdx.x;
    float* crow = cat + (size_t)q*CATC;

    for (int f = tid; f < 4608; f += 192) {
        int hh = f / 384, k = f % 384;
        abuf[hh*385 + k] = lg[(size_t)hh*NN + (size_t)q*NRES + half*384 + k];
    }
    __syncthreads();
    if (half == 0 && tid < 96) {
        int hh = tid>>3, p = tid&7;
        float b0 = optt[(size_t)q*288 + hh*24+p*3+0] - trans[q*3+0];
        float b1 = optt[(size_t)q*288 + hh*24+p*3+1] - trans[q*3+1];
        float b2 = optt[(size_t)q*288 + hh*24+p*3+2] - trans[q*3+2];
        const float* Rm = rot + (size_t)q*9;
        float v0 = Rm[0]*b0 + Rm[3]*b1 + Rm[6]*b2;
        float v1 = Rm[1]*b0 + Rm[4]*b1 + Rm[7]*b2;
        float v2 = Rm[2]*b0 + Rm[5]*b1 + Rm[8]*b2;
        crow[192 + tid] = v0;
        crow[288 + tid] = v1;
        crow[384 + tid] = v2;
        crow[480 + tid] = sqrtf(v0*v0 + v1*v1 + v2*v2 + 1e-8f);
    }
    const int h = tid >> 4, c8 = (tid & 15)*8;
    const unsigned* zq = (const unsigned*)zh + ((size_t)(q*768 + half*384))*64 + (tid & 15)*4;
    const float* ah = abuf + h*385;
    float a0=0,a1=0,a2=0,a3=0,a4=0,a5=0,a6=0,a7=0;
    #pragma unroll 4
    for (int k = 0; k < 384; ++k) {
        float aw = ah[k];
        uint4 zv = *(const uint4*)(zq + (size_t)k*64);
        a0 += aw*BFLO(zv.x); a1 += aw*BFHI(zv.x);
        a2 += aw*BFLO(zv.y); a3 += aw*BFHI(zv.y);
        a4 += aw*BFLO(zv.z); a5 += aw*BFHI(zv.z);
        a6 += aw*BFLO(zv.w); a7 += aw*BFHI(zv.w);
    }
    float* dst = crow + 576 + h*128 + c8;
    atomicAdd(dst+0, a0); atomicAdd(dst+1, a1);
    atomicAdd(dst+2, a2); atomicAdd(dst+3, a3);
    atomicAdd(dst+4, a4); atomicAdd(dst+5, a5);
    atomicAdd(dst+6, a6); atomicAdd(dst+7, a7);
}

// ---------------- outgemm: 64x64 tile, 4x4 micro, split-K=6, atomicAdd ----------------
__global__ __launch_bounds__(256) void outgemm_kernel(
    const float* __restrict__ cat, const float* __restrict__ W_out,
    float* __restrict__ out)
{
    __shared__ float Al[32][68];   // [k][m]
    __shared__ float Bl[32][68];   // [k][n]
    const int mt = blockIdx.x;     // 0..11
    const int nt = blockIdx.y;     // 0..5
    const int kt = blockIdx.z;     // 0..5 (352 K each)
    const int tid = threadIdx.x;
    const int m0 = (tid & 15)*4, n0 = (tid >> 4)*4;
    float acc[4][4] = {};
    for (int ki = 0; ki < 11; ++ki) {
        int kc = kt*352 + ki*32;
        #pragma unroll
        for (int f = tid; f < 512; f += 256) {
            int r = f >> 3, c4 = (f & 7)*4;
            float4 v = *(const float4*)(cat + (size_t)(mt*64+r)*CATC + kc + c4);
            Al[c4][r]=v.x; Al[c4+1][r]=v.y; Al[c4+2][r]=v.z; Al[c4+3][r]=v.w;
        }
        #pragma unroll
        for (int f = tid; f < 512; f += 256) {
            int r = f >> 4, c4 = (f & 15)*4;
            *(float4*)&Bl[r][c4] = *(const float4*)(W_out + (size_t)(kc+r)*CS + nt*64 + c4);
        }
        __syncthreads();
        #pragma unroll
        for (int kk = 0; kk < 32; ++kk) {
            float4 a = *(const float4*)&Al[kk][m0];
            float4 b = *(const float4*)&Bl[kk][n0];
            acc[0][0]+=a.x*b.x; acc[0][1]+=a.x*b.y; acc[0][2]+=a.x*b.z; acc[0][3]+=a.x*b.w;
            acc[1][0]+=a.y*b.x; acc[1][1]+=a.y*b.y; acc[1][2]+=a.y*b.z; acc[1][3]+=a.y*b.w;
            acc[2][0]+=a.z*b.x; acc[2][1]+=a.z*b.y; acc[2][2]+=a.z*b.z; acc[2][3]+=a.z*b.w;
            acc[3][0]+=a.w*b.x; acc[3][1]+=a.w*b.y; acc[3][2]+=a.w*b.z; acc[3][3]+=a.w*b.w;
        }
        __syncthreads();
    }
    #pragma unroll
    for (int r = 0; r < 4; ++r)
        #pragma unroll
        for (int c = 0; c < 4; ++c)
            atomicAdd(&out[(size_t)(mt*64+m0+r)*CS + nt*64+n0+c], acc[r][c]);
}

extern "C" void kernel_launch(void* const* d_in, const int* in_sizes, int n_in,
                              void* d_out, int out_size, void* d_ws, size_t ws_size,
                              hipStream_t stream) {
    const float* s      = (const float*)d_in[0];
    const float* z      = (const float*)d_in[1];
    const float* rot    = (const float*)d_in[2];
    const float* trans  = (const float*)d_in[3];
    const float* mask   = (const float*)d_in[4];
    const float* W_q    = (const float*)d_in[5];
    const float* b_q    = (const float*)d_in[6];
    const float* W_kv   = (const float*)d_in[7];
    const float* b_kv   = (const float*)d_in[8];
    const float* W_qp   = (const float*)d_in[9];
    const float* b_qp   = (const float*)d_in[10];
    const float* W_kvp  = (const float*)d_in[11];
    const float* b_kvp  = (const float*)d_in[12];
    const float* W_b    = (const float*)d_in[13];
    const float* b_b    = (const float*)d_in[14];
    const float* head_w = (const float*)d_in[15];
    const float* W_out  = (const float*)d_in[16];
    const float* b_out  = (const float*)d_in[17];

    float* ws = (float*)d_ws;
    // lg occupies [0, 7077888); proj_* alias its head (dead before bias_kernel writes lg)
    float* lg       = ws;
    float* proj_q   = ws;                 // 147456
    float* proj_kv  = ws + 147456;        // 294912
    float* proj_qp  = ws + 442368;        // 110592
    float* proj_kvp = ws + 552960;        // 331776 (ends 884736 < 7077888)
    float* vcatT    = ws + 7077888;       // 368640
    float* qfrag    = ws + 7446528;       // 258048
    float* kcat     = ws + 7704576;       // 258048
    float* optt     = ws + 7962624;       // 221184
    float* cat      = ws + 8183808;       // 1622016 (ends 9805824)
    unsigned short* zh = (unsigned short*)(ws + 9805824);  // 75497472 bf16 = 151 MB
    float* out = (float*)d_out;

    proj_kernel<<<dim3(24,24), 256, 0, stream>>>(s, W_q, b_q, W_kv, b_kv, W_qp, b_qp, W_kvp, b_kvp,
                                                 proj_q, proj_kv, proj_qp, proj_kvp);
    rotpts_kernel<<<8928, 256, 0, stream>>>(rot, trans, proj_q, proj_kv, proj_qp, proj_kvp, b_out,
                                            qfrag, kcat, vcatT, out, cat);
    bias_kernel<<<NN/256, 256, 0, stream>>>(z, mask, W_b, b_b, lg, zh);
    softmax_fused_kernel<<<12*(NRES/8), 512, 0, stream>>>(lg, qfrag, kcat, head_w, vcatT, cat, optt);
    opair_kernel<<<NRES*2, 192, 0, stream>>>(zh, lg, rot, trans, optt, cat);
    outgemm_kernel<<<dim3(12,6,6), 256, 0, stream>>>(cat, W_out, out);
}